// Round 1
// baseline (18470.786 us; speedup 1.0000x reference)
//
#include <hip/hip_runtime.h>

#define BATCH 32
#define SEQ   2048
#define ISZ   512
#define HSZ   512
#define GRID  256
#define TPB   512
#define SPIN_CAP 2000000
#define CANARY 0x7fc0deadu   // quiet NaN bit pattern; LSTM h is always finite

typedef unsigned long long u64;
typedef unsigned int u32;

// Sync protocol (canary data-poll): the whole h region of `out` is pre-filled
// with a NaN canary each launch. Producer stores its h[t] slice with relaxed
// agent-scope stores and does NOTHING else (no ack, no beacon). Each consumer
// thread polls the exact 32 B it needs from h[t-1] until all 8 dwords are
// non-canary -- each dword independently self-tags, so partial arrival is
// safe, and when the poll hits the data is already in registers (the former
// beacon RT + ack RT + separate bulk-read RT collapse into one round trip).
// Every (t,b,d) cell is written exactly once => monotone, no ABA.

__device__ __forceinline__ u64 ld_agent_u64(const u64* p) {
    return __hip_atomic_load(p, __ATOMIC_RELAXED, __HIP_MEMORY_SCOPE_AGENT);
}
__device__ __forceinline__ void st_agent_f32(float* p, float v) {
    __hip_atomic_store(p, v, __ATOMIC_RELAXED, __HIP_MEMORY_SCOPE_AGENT);
}
__device__ __forceinline__ float u2f(u32 u) { union { u32 u; float f; } c; c.u = u; return c.f; }
__device__ __forceinline__ int ok64(u64 v) {
    return ((u32)v != CANARY) & ((u32)(v >> 32) != CANARY);
}

__global__ __launch_bounds__(TPB)
void lstm_persistent(const float* __restrict__ inp,
                     const float* __restrict__ w_ii, const float* __restrict__ w_hi,
                     const float* __restrict__ b_ii, const float* __restrict__ b_hi,
                     const float* __restrict__ w_if, const float* __restrict__ w_hf,
                     const float* __restrict__ b_if, const float* __restrict__ b_hf,
                     const float* __restrict__ w_io, const float* __restrict__ w_ho,
                     const float* __restrict__ b_io, const float* __restrict__ b_ho,
                     const float* __restrict__ w_ig, const float* __restrict__ w_hg,
                     const float* __restrict__ b_ig, const float* __restrict__ b_hg,
                     float* __restrict__ out, u32* __restrict__ beac)
{
    __shared__ float lh[8 * 512];           // staged h[t-1], XOR-swizzled (16 KB)
    __shared__ float gpre[32][9];           // [row][batch] gate preactivations
    __shared__ float lbias[32];

    const int tid = threadIdx.x;
    const int g   = blockIdx.x;
    const int bg  = g & 3;                  // batch group (8 batches)
    const int b0  = bg * 8;
    const int p   = g >> 2;                 // producer index (0..63)
    const int d0  = p * 8;                  // this block's 8 h-dims

    const int rp = tid >> 5;                // row pair (rows 2rp,2rp+1 of 32)
    const int ks = tid & 31;                // 16-float k-slice
    const int r0 = 2 * rp;                  // gpre row (= gate*8 + dl0)
    const int gg = r0 >> 3;                 // gate index
    const int dl0 = r0 & 7, dl1 = dl0 + 1;  // local dims within the 8
    const int xr  = (ks >> 1) & 7;          // hdot XOR term: ((4ks+j)>>3)&7
    // poll / staging ids
    const int bb = tid >> 6;                // batch 0..7
    const int cc = tid & 63;                // 8-float chunk 0..63 (== producer idx)

    const float* whp[4] = { w_hi, w_hf, w_hg, w_ho };
    const float* wxp[4] = { w_ii, w_if, w_ig, w_io };
    const float* bip[4] = { b_ii, b_if, b_ig, b_io };
    const float* bhp[4] = { b_hi, b_hf, b_hg, b_ho };

    if (tid < 32) {
        int g2 = tid >> 3, d2 = tid & 7;
        lbias[tid] = bip[g2][d0 + d2] + bhp[g2][d0 + d2];
    }

    // weights in registers: 2 rows x 16-float slice of Wx and Wh = 64 floats
    float4 wx0[4], wx1[4], wh0[4], wh1[4];
    {
        const float* x0 = wxp[gg] + (size_t)(d0 + dl0) * 512 + ks * 16;
        const float* x1 = wxp[gg] + (size_t)(d0 + dl1) * 512 + ks * 16;
        const float* h0 = whp[gg] + (size_t)(d0 + dl0) * 512 + ks * 16;
        const float* h1 = whp[gg] + (size_t)(d0 + dl1) * 512 + ks * 16;
        #pragma unroll
        for (int j = 0; j < 4; ++j) {
            wx0[j] = *(const float4*)(x0 + 4 * j);
            wx1[j] = *(const float4*)(x1 + 4 * j);
            wh0[j] = *(const float4*)(h0 + 4 * j);
            wh1[j] = *(const float4*)(h1 + 4 * j);
        }
    }
    __syncthreads();

    float xpc0[8], xpc1[8], xpn0[8], xpn1[8];

    // x-projection of step tt, batches [blo,bhi) -> xpn (or xpc via pointer)
    auto xproj = [&](int tt, int blo, int bhi, float* q0, float* q1) {
        for (int b = blo; b < bhi; ++b) {
            const float* src = inp + ((size_t)(b0 + b) * SEQ + tt) * ISZ + ks * 16;
            float4 o0 = *(const float4*)(src);
            float4 o1 = *(const float4*)(src + 4);
            float4 o2 = *(const float4*)(src + 8);
            float4 o3 = *(const float4*)(src + 12);
            float a0 = 0.f, a1 = 0.f;
            a0 = fmaf(wx0[0].x,o0.x,a0); a0 = fmaf(wx0[0].y,o0.y,a0); a0 = fmaf(wx0[0].z,o0.z,a0); a0 = fmaf(wx0[0].w,o0.w,a0);
            a0 = fmaf(wx0[1].x,o1.x,a0); a0 = fmaf(wx0[1].y,o1.y,a0); a0 = fmaf(wx0[1].z,o1.z,a0); a0 = fmaf(wx0[1].w,o1.w,a0);
            a0 = fmaf(wx0[2].x,o2.x,a0); a0 = fmaf(wx0[2].y,o2.y,a0); a0 = fmaf(wx0[2].z,o2.z,a0); a0 = fmaf(wx0[2].w,o2.w,a0);
            a0 = fmaf(wx0[3].x,o3.x,a0); a0 = fmaf(wx0[3].y,o3.y,a0); a0 = fmaf(wx0[3].z,o3.z,a0); a0 = fmaf(wx0[3].w,o3.w,a0);
            a1 = fmaf(wx1[0].x,o0.x,a1); a1 = fmaf(wx1[0].y,o0.y,a1); a1 = fmaf(wx1[0].z,o0.z,a1); a1 = fmaf(wx1[0].w,o0.w,a1);
            a1 = fmaf(wx1[1].x,o1.x,a1); a1 = fmaf(wx1[1].y,o1.y,a1); a1 = fmaf(wx1[1].z,o1.z,a1); a1 = fmaf(wx1[1].w,o1.w,a1);
            a1 = fmaf(wx1[2].x,o2.x,a1); a1 = fmaf(wx1[2].y,o2.y,a1); a1 = fmaf(wx1[2].z,o2.z,a1); a1 = fmaf(wx1[2].w,o2.w,a1);
            a1 = fmaf(wx1[3].x,o3.x,a1); a1 = fmaf(wx1[3].y,o3.y,a1); a1 = fmaf(wx1[3].z,o3.z,a1); a1 = fmaf(wx1[3].w,o3.w,a1);
            q0[b] = a0; q1[b] = a1;
        }
    };

    xproj(0, 0, 8, xpc0, xpc1);             // prologue

    float h_keep = 0.f, c_keep = 0.f, c_reg = 0.f;

    for (int t = 0; t < SEQ; ++t) {
        if (t > 0) {
            // ---- 1: issue poll load of this thread's 32 B of h[t-1] ----
            const u64* src64 = (const u64*)(out + (size_t)(t - 1) * BATCH * HSZ
                                                + (size_t)(b0 + bb) * HSZ + cc * 8);
            u64 v0 = ld_agent_u64(src64 + 0);
            u64 v1 = ld_agent_u64(src64 + 1);
            u64 v2 = ld_agent_u64(src64 + 2);
            u64 v3 = ld_agent_u64(src64 + 3);

            // ---- 2: first half of xproj(t+1) hides the poll latency ----
            if (t + 1 < SEQ) xproj(t + 1, 0, 4, xpn0, xpn1);

            // ---- 3: canary poll -- data in registers on exit ----
            int spin = 0;
            while (!(ok64(v0) & ok64(v1) & ok64(v2) & ok64(v3))) {
                __builtin_amdgcn_s_sleep(1);
                v0 = ld_agent_u64(src64 + 0);
                v1 = ld_agent_u64(src64 + 1);
                v2 = ld_agent_u64(src64 + 2);
                v3 = ld_agent_u64(src64 + 3);
                if (++spin > SPIN_CAP) break;
            }

            // ---- 4: second half of xproj(t+1) ----
            if (t + 1 < SEQ) xproj(t + 1, 4, 8, xpn0, xpn1);

            // ---- 5: stage into LDS, XOR-swizzled at float4 granularity ----
            float4 wA, wB;
            wA.x = u2f((u32)v0); wA.y = u2f((u32)(v0 >> 32));
            wA.z = u2f((u32)v1); wA.w = u2f((u32)(v1 >> 32));
            wB.x = u2f((u32)v2); wB.y = u2f((u32)(v2 >> 32));
            wB.z = u2f((u32)v3); wB.w = u2f((u32)(v3 >> 32));
            const int qA = 2 * cc, qB = 2 * cc + 1;
            *(float4*)(&lh[bb * 512 + (qA ^ ((qA >> 3) & 7)) * 4]) = wA;
            *(float4*)(&lh[bb * 512 + (qB ^ ((qB >> 3) & 7)) * 4]) = wB;
            __syncthreads();                // (S) all slices staged
        } else {
            if (t + 1 < SEQ) { xproj(t + 1, 0, 4, xpn0, xpn1); xproj(t + 1, 4, 8, xpn0, xpn1); }
        }

        // ---- 6: h-dot on top of fused x partials, single reduction ----
        #pragma unroll
        for (int b = 0; b < 8; ++b) {
            float a0 = xpc0[b], a1 = xpc1[b];
            if (t > 0) {
                const float* hb = &lh[b * 512];
                float4 o0 = *(const float4*)(hb + ((4 * ks + 0) ^ xr) * 4);
                float4 o1 = *(const float4*)(hb + ((4 * ks + 1) ^ xr) * 4);
                float4 o2 = *(const float4*)(hb + ((4 * ks + 2) ^ xr) * 4);
                float4 o3 = *(const float4*)(hb + ((4 * ks + 3) ^ xr) * 4);
                a0 = fmaf(wh0[0].x,o0.x,a0); a0 = fmaf(wh0[0].y,o0.y,a0); a0 = fmaf(wh0[0].z,o0.z,a0); a0 = fmaf(wh0[0].w,o0.w,a0);
                a0 = fmaf(wh0[1].x,o1.x,a0); a0 = fmaf(wh0[1].y,o1.y,a0); a0 = fmaf(wh0[1].z,o1.z,a0); a0 = fmaf(wh0[1].w,o1.w,a0);
                a0 = fmaf(wh0[2].x,o2.x,a0); a0 = fmaf(wh0[2].y,o2.y,a0); a0 = fmaf(wh0[2].z,o2.z,a0); a0 = fmaf(wh0[2].w,o2.w,a0);
                a0 = fmaf(wh0[3].x,o3.x,a0); a0 = fmaf(wh0[3].y,o3.y,a0); a0 = fmaf(wh0[3].z,o3.z,a0); a0 = fmaf(wh0[3].w,o3.w,a0);
                a1 = fmaf(wh1[0].x,o0.x,a1); a1 = fmaf(wh1[0].y,o0.y,a1); a1 = fmaf(wh1[0].z,o0.z,a1); a1 = fmaf(wh1[0].w,o0.w,a1);
                a1 = fmaf(wh1[1].x,o1.x,a1); a1 = fmaf(wh1[1].y,o1.y,a1); a1 = fmaf(wh1[1].z,o1.z,a1); a1 = fmaf(wh1[1].w,o1.w,a1);
                a1 = fmaf(wh1[2].x,o2.x,a1); a1 = fmaf(wh1[2].y,o2.y,a1); a1 = fmaf(wh1[2].z,o2.z,a1); a1 = fmaf(wh1[2].w,o2.w,a1);
                a1 = fmaf(wh1[3].x,o3.x,a1); a1 = fmaf(wh1[3].y,o3.y,a1); a1 = fmaf(wh1[3].z,o3.z,a1); a1 = fmaf(wh1[3].w,o3.w,a1);
            }
            #pragma unroll
            for (int m = 16; m >= 1; m >>= 1) {
                a0 += __shfl_xor(a0, m);
                a1 += __shfl_xor(a1, m);
            }
            if ((tid & 31) == 0) {
                gpre[r0][b]     = a0;
                gpre[r0 + 1][b] = a1;
            }
        }
        __syncthreads();                    // (B) gates ready; lh free next iter

        // ---- 7: nonlinearity + agent h store (no ack, no beacon) ----
        if (tid < 64) {
            int b = tid >> 3, dl = tid & 7;
            float iv = gpre[0  + dl][b] + lbias[0  + dl];
            float fv = gpre[8  + dl][b] + lbias[8  + dl];
            float gv = gpre[16 + dl][b] + lbias[16 + dl];
            float ov = gpre[24 + dl][b] + lbias[24 + dl];
            iv = 1.f / (1.f + __expf(-iv));
            fv = 1.f / (1.f + __expf(-fv));
            gv = tanhf(gv);
            ov = 1.f / (1.f + __expf(-ov));
            float c = fv * c_reg + iv * gv;
            float h = ov * tanhf(c);
            c_reg = c; h_keep = h; c_keep = c;
            st_agent_f32(out + (size_t)t * BATCH * HSZ + (size_t)(b0 + b) * HSZ + (d0 + dl), h);
        }

        #pragma unroll
        for (int b = 0; b < 8; ++b) { xpc0[b] = xpn0[b]; xpc1[b] = xpn1[b]; }
    }

    if (tid < 64) {
        int b = tid >> 3, dl = tid & 7;
        size_t base = (size_t)SEQ * BATCH * HSZ;
        out[base + (size_t)(b0 + b) * HSZ + (d0 + dl)] = h_keep;                        // h_last
        out[base + (size_t)BATCH * HSZ + (size_t)(b0 + b) * HSZ + (d0 + dl)] = c_keep;  // c_last
    }
}

extern "C" void kernel_launch(void* const* d_in, const int* in_sizes, int n_in,
                              void* d_out, int out_size, void* d_ws, size_t ws_size,
                              hipStream_t stream) {
    const float* inp  = (const float*)d_in[0];
    const float* w_ii = (const float*)d_in[1];
    const float* w_hi = (const float*)d_in[2];
    const float* b_ii = (const float*)d_in[3];
    const float* b_hi = (const float*)d_in[4];
    const float* w_if = (const float*)d_in[5];
    const float* w_hf = (const float*)d_in[6];
    const float* b_if = (const float*)d_in[7];
    const float* b_hf = (const float*)d_in[8];
    const float* w_io = (const float*)d_in[9];
    const float* w_ho = (const float*)d_in[10];
    const float* b_io = (const float*)d_in[11];
    const float* b_ho = (const float*)d_in[12];
    const float* w_ig = (const float*)d_in[13];
    const float* w_hg = (const float*)d_in[14];
    const float* b_ig = (const float*)d_in[15];
    const float* b_hg = (const float*)d_in[16];
    float* out = (float*)d_out;
    u32* beac = (u32*)d_ws;

    // Canary-fill the h region (steps 0..SEQ-1) so consumers can poll data
    // directly; every cell is overwritten by its producer exactly once.
    hipMemsetD32Async((hipDeviceptr_t)out, (int)CANARY,
                      (size_t)SEQ * BATCH * HSZ, stream);

    void* args[] = { (void*)&inp,
                     (void*)&w_ii, (void*)&w_hi, (void*)&b_ii, (void*)&b_hi,
                     (void*)&w_if, (void*)&w_hf, (void*)&b_if, (void*)&b_hf,
                     (void*)&w_io, (void*)&w_ho, (void*)&b_io, (void*)&b_ho,
                     (void*)&w_ig, (void*)&w_hg, (void*)&b_ig, (void*)&b_hg,
                     (void*)&out, (void*)&beac };
    hipError_t err = hipLaunchCooperativeKernel((const void*)lstm_persistent,
                                                dim3(GRID), dim3(TPB), args, 0, stream);
    if (err != hipSuccess) {
        lstm_persistent<<<dim3(GRID), dim3(TPB), 0, stream>>>(
            inp, w_ii, w_hi, b_ii, b_hi, w_if, w_hf, b_if, b_hf,
            w_io, w_ho, b_io, b_ho, w_ig, w_hg, b_ig, b_hg, out, beac);
    }
}